// Round 1
// 79.114 us; speedup vs baseline: 1.0060x; 1.0060x over previous
//
#include <hip/hip_runtime.h>
#include <math.h>

#define NPTS 2048
#define NG 2
#define IMG_H 512
#define IMG_W 512
#define HW (IMG_H * IMG_W)
#define RENDER_SIZE (3 * HW)
// ln(255): sigma above this -> alpha < 1/255 -> contribution exactly zeroed
#define S_MAX 5.5412636f

#define TILE_W 32
#define TILE_H 8
#define TILES_X (IMG_W / TILE_W)    // 16
#define TILES_Y (IMG_H / TILE_H)    // 64
#define NTILES (TILES_X * TILES_Y)  // 1024 (== NPTS/2, each block owns 2 radii)
#define NTHREADS 256                // one thread per tile pixel
#define CAP 128                     // per-tile point list capacity (avg ~5 hits)

__device__ __forceinline__ float sigmoidf_(float x) {
    return 1.0f / (1.0f + expf(-x));
}

// Per-point render parameters staged in LDS (16 floats = 4 x ds_read_b128 broadcast).
struct PParam {
    float xn, yn, ca, cb, cc, op;
    float c0, c1, c2;
    float fx0, fy0, fx1, fy1, w0, w1, pad;
};

__global__ __launch_bounds__(NTHREADS) void render_kernel(
    const float* __restrict__ xyz, const float* __restrict__ cov2d,
    const float* __restrict__ fdc, const float* __restrict__ opac,
    const float* __restrict__ gfreq, const float* __restrict__ gwts,
    float* __restrict__ out)
{
    __shared__ int s_cnt;
    __shared__ int s_idx[CAP];
    __shared__ PParam s_prm[CAP];

    const int tid = threadIdx.x;
    const int tile = blockIdx.x;
    const int x0 = (tile % TILES_X) * TILE_W;
    const int y0 = (tile / TILES_X) * TILE_H;

    if (tid == 0) s_cnt = 0;

    // ---- radii + visibility: 2 points per block, exact __f*_rn sequence ----
    if (tid < 2) {
        int i = tile * 2 + tid;  // NTILES*2 == NPTS
        float sxx = cov2d[i * 3 + 0] + 0.5f;
        float sxy = cov2d[i * 3 + 1];
        float syy = cov2d[i * 3 + 2] + 0.5f;
        // Block FMA contraction so fp32 rounding matches numpy through ceil().
        float det = __fsub_rn(__fmul_rn(sxx, syy), __fmul_rn(sxy, sxy));
        bool valid = det > 1e-8f;
        float mid = __fmul_rn(0.5f, __fadd_rn(sxx, syy));
        float t = __fsub_rn(__fmul_rn(mid, mid), det);
        t = fmaxf(t, 0.1f);
        float lam = __fadd_rn(mid, sqrtf(t));
        float r = valid ? ceilf(__fmul_rn(3.0f, sqrtf(lam))) : 0.0f;
        out[RENDER_SIZE + i] = r;                               // radii
        out[RENDER_SIZE + NPTS + i] = (r > 0.0f) ? 1.0f : 0.0f; // visibility
    }
    __syncthreads();

    // ---- phase 1: cull all points against this tile ----
    // Separable ellipse bound: on {sigma <= S}, max dx^2 = 2*S*sxx (dy analog).
    // A point excluded here has alpha < 1/255 for every pixel of the tile
    // (opacity <= 1), i.e. exactly the pixels the reference zeroes anyway.
    const float txlo = x0 + 0.5f, txhi = x0 + (TILE_W - 1) + 0.5f;
    const float tylo = y0 + 0.5f, tyhi = y0 + (TILE_H - 1) + 0.5f;
    for (int p = tid; p < NPTS; p += NTHREADS) {
        float2 c = ((const float2*)xyz)[p];
        float sxx = cov2d[p * 3 + 0] + 0.5f;
        float sxy = cov2d[p * 3 + 1];
        float syy = cov2d[p * 3 + 2] + 0.5f;
        float det = sxx * syy - sxy * sxy;
        if (!(det > 1e-8f)) continue;  // invalid -> alpha forced to 0 everywhere
        float dxn = fmaxf(0.0f, fmaxf(txlo - c.x, c.x - txhi));
        float dyn = fmaxf(0.0f, fmaxf(tylo - c.y, c.y - tyhi));
        // +0.25f slop (squared px) over-approximates the old +0.01px border;
        // false positives are harmless (per-pixel alpha test below).
        if (dxn * dxn <= 2.0f * S_MAX * sxx + 0.25f &&
            dyn * dyn <= 2.0f * S_MAX * syy + 0.25f) {
            int slot = atomicAdd(&s_cnt, 1);
            if (slot < CAP) s_idx[slot] = p;
        }
    }
    __syncthreads();
    const int n = min(s_cnt, CAP);

    // ---- phase 2: cooperatively expand survivor params into LDS ----
    for (int i = tid; i < n; i += NTHREADS) {
        int p = s_idx[i];
        float sxx = cov2d[p * 3 + 0] + 0.5f;
        float sxy = cov2d[p * 3 + 1];
        float syy = cov2d[p * 3 + 2] + 0.5f;
        float inv = 1.0f / (sxx * syy - sxy * sxy);
        PParam q;
        q.xn = xyz[p * 2 + 0];
        q.yn = xyz[p * 2 + 1];
        q.ca = syy * inv;
        q.cb = -sxy * inv;
        q.cc = sxx * inv;
        q.op = opac[p];
        q.c0 = sigmoidf_(fdc[p * 3 + 0]);
        q.c1 = sigmoidf_(fdc[p * 3 + 1]);
        q.c2 = sigmoidf_(fdc[p * 3 + 2]);
        q.fx0 = expf(gfreq[(p * NG + 0) * 2 + 0]);
        q.fy0 = expf(gfreq[(p * NG + 0) * 2 + 1]);
        q.fx1 = expf(gfreq[(p * NG + 1) * 2 + 0]);
        q.fy1 = expf(gfreq[(p * NG + 1) * 2 + 1]);
        q.w0 = sigmoidf_(gwts[p * NG + 0]);
        q.w1 = sigmoidf_(gwts[p * NG + 1]);
        q.pad = 0.0f;
        s_prm[i] = q;
    }
    __syncthreads();

    // ---- phase 3: per-pixel gather, clamp, single coalesced store ----
    const int tx = tid % TILE_W;
    const int ty = tid / TILE_W;
    const float px = x0 + tx + 0.5f;
    const float py = y0 + ty + 0.5f;
    float accr = 0.0f, accg = 0.0f, accb = 0.0f;
    for (int i = 0; i < n; ++i) {
        PParam q = s_prm[i];  // uniform index -> LDS broadcast, conflict-free
        float dx = px - q.xn;
        float dy = py - q.yn;
        // Byte-identical expressions to the verified scatter kernel:
        float sigma = 0.5f * (q.ca * dx * dx + q.cc * dy * dy) + q.cb * (dx * dy);
        float alpha = q.op * expf(-sigma);
        alpha = fminf(alpha, 0.999f);
        if (alpha < (1.0f / 255.0f)) continue;  // exact reference threshold
        float mod = 1.0f + q.w0 * cosf(q.fx0 * dx + q.fy0 * dy)
                         + q.w1 * cosf(q.fx1 * dx + q.fy1 * dy);
        float wgt = alpha * mod;
        accr += wgt * q.c0;
        accg += wgt * q.c1;
        accb += wgt * q.c2;
    }
    const int pix = (y0 + ty) * IMG_W + (x0 + tx);
    out[pix]          = fminf(fmaxf(accr, 0.0f), 1.0f);
    out[HW + pix]     = fminf(fmaxf(accg, 0.0f), 1.0f);
    out[2 * HW + pix] = fminf(fmaxf(accb, 0.0f), 1.0f);
}

extern "C" void kernel_launch(void* const* d_in, const int* in_sizes, int n_in,
                              void* d_out, int out_size, void* d_ws, size_t ws_size,
                              hipStream_t stream) {
    const float* xyz   = (const float*)d_in[0];
    const float* cov2d = (const float*)d_in[1];
    const float* fdc   = (const float*)d_in[2];
    const float* opac  = (const float*)d_in[3];
    const float* gfreq = (const float*)d_in[4];
    const float* gwts  = (const float*)d_in[5];
    // d_in[6] = background (unused by the render), d_in[7]=H, d_in[8]=W
    float* out = (float*)d_out;

    render_kernel<<<NTILES, NTHREADS, 0, stream>>>(
        xyz, cov2d, fdc, opac, gfreq, gwts, out);
}